// Round 12
// baseline (84.661 us; speedup 1.0000x reference)
//
#include <hip/hip_runtime.h>
#include <math.h>

namespace {

constexpr int RAD  = 6;
constexpr int P    = 13;
constexpr int NWIN = 169;   // P*P
constexpr int NTOT = 338;   // 2 refs * NWIN
constexpr int NCH  = 128;
constexpr int NCLS = 32;
constexpr int W    = 64;
constexpr int HW   = 4096;
constexpr float FOUR_LN2 = 2.772588722239781f;

// ---- padded fr copy ----
constexpr int PADH = 76;             // rows 0..75 = logical y -6..69
constexpr int PADW = 80;             // cols: logical x at col x+6 (left pad 6, right 10)
constexpr int PADCH = PADH * PADW;   // 6080 floats per channel
// staged window for block at x0: padded cols [x0, x0+48) = logical x0-6 .. x0+41

// ---- kernel A tiling (R9-proven geometry) ----
constexpr int TX    = 32;            // pixels per block (half row)
constexpr int CHUNK = 8;             // channels per stage
constexpr int PW    = 48;            // patch width
constexpr int PR    = 13;            // patch rows (dy)
constexpr int FRELEMS = CHUNK * PR * PW;   // 4992 floats
constexpr int NV4   = FRELEMS / 4;         // 1248 float4
constexpr int NCHUNK = NCH / CHUNK;  // 16
constexpr int TILE  = TX * NWIN;     // 5408 floats
constexpr size_t VOLF = (size_t)2 * HW * NTOT;  // floats in volume

__device__ __forceinline__ bool better(float va, int ia, float vb, int ib) {
  return (va > vb) || ((va == vb) && (ia < ib));
}

// ================= Kernel P: pad fr + label map =================
// frp[(ii*2+b)*128 + c][yy][xx] ; 778240 float4s over 3040 blocks.
__global__ __launch_bounds__(256) void pad_kernel(
    const float* __restrict__ fr, const int* __restrict__ q,
    float* __restrict__ frp, int* __restrict__ lab) {
  const int gid = blockIdx.x * 256 + threadIdx.x;   // 0 .. 778239
  const int xx4 = gid % 20;
  const int row = gid / 20;
  const int yy  = row % PADH;
  const int cr  = row / PADH;        // 0..511 = (ii*2+b)*128 + c
  const int ly  = yy - 6;
  float4 v;
  float* vp = (float*)&v;
  const float* src = fr + (size_t)cr * HW + ly * W;
  #pragma unroll
  for (int j = 0; j < 4; ++j) {
    const int lx = xx4 * 4 + j - 6;
    vp[j] = ((unsigned)ly < 64u && (unsigned)lx < 64u) ? src[lx] : 0.f;
  }
  *(float4*)(frp + (size_t)gid * 4) = v;

  if (gid < 16384) {                  // fold in label map
    const int i2b = gid >> 12;
    const int rem = gid & 4095;
    const int y2  = rem >> 6;
    const int x2  = rem & 63;
    lab[gid] = q[(size_t)i2b * 65536 + (y2 * 4) * 256 + x2 * 4];
  }
}

// ================= Kernel A: correlation volume =================
// grid: ((b*2+i)*64 + y)*2 + xh   (512 blocks), 256 threads
// float4 staging from padded fr (no masking), single barrier per chunk.
__global__ __launch_bounds__(256, 2) void corr_kernel(
    const float* __restrict__ frp,  // padded [4][128][76][80]
    const float* __restrict__ ft,   // [2][128][64][64]
    float* __restrict__ vol) {
  const int blk = blockIdx.x;
  const int xh = blk & 1;
  const int y  = (blk >> 1) & 63;
  const int bi = blk >> 7;             // b*2+i
  const int b  = bi >> 1;
  const int ii = bi & 1;
  const int x0 = xh * TX;
  const int t  = threadIdx.x;
  const int cg = t >> 7;               // channel group 0/1
  const int tl = t & 127;

  __shared__ __align__(16) float smem[2 * FRELEMS];     // 39936 B
  __shared__ __align__(16) float ftbuf[2][CHUNK * TX];  // 2048 B

  const int xg = tl & 7;               // x-quad within half row
  const int dy = tl >> 3;              // 0..12 valid when tl<104
  const bool comp = (tl < 104);
  const bool tail = (t < NV4 - 1024);  // u==4 guard (224 threads)

  const float* frpbase = frp + (size_t)((ii * 2 + b) * NCH) * PADCH;
  // ft float4 staging: thread t<64 loads channel (t>>3), quad (t&7)
  const float* ftp4 = ft + (size_t)(b * NCH + (t >> 3)) * HW + y * W + x0 + (t & 7) * 4;

  // ---- hoisted staging offsets (float4 granules, loop-invariant) ----
  int off4[5];
  #pragma unroll
  for (int u = 0; u < 5; ++u) {
    const int e4 = t + u * 256;
    const int cc  = e4 / 156;          // float4s per channel-chunk-row-block: 13*12
    const int rem = e4 - cc * 156;
    const int r   = rem / 12;
    const int xc4 = rem - r * 12;
    off4[u] = cc * PADCH + (y + r) * PADW + x0 + xc4 * 4;
  }

  float acc[13][4];
  #pragma unroll
  for (int dx = 0; dx < 13; ++dx)
    #pragma unroll
    for (int k = 0; k < 4; ++k) acc[dx][k] = 0.f;

  float4 rg4[5];
  float4 rft4;

  auto stage_load = [&](int c0) {
    const float* fb = frpbase + (size_t)c0 * PADCH;
    #pragma unroll
    for (int u = 0; u < 5; ++u)
      if (u < 4 || tail) rg4[u] = *(const float4*)(fb + off4[u]);
    if (t < 64) rft4 = *(const float4*)(ftp4 + (size_t)c0 * HW);
  };
  auto stage_write = [&](int s) {
    float* frb = smem + s * FRELEMS;
    #pragma unroll
    for (int u = 0; u < 5; ++u)
      if (u < 4 || tail) *(float4*)(frb + (t + u * 256) * 4) = rg4[u];
    if (t < 64) *(float4*)(&ftbuf[s][(t >> 3) * TX + (t & 7) * 4]) = rft4;
  };

  stage_load(0);
  stage_write(0);
  __syncthreads();

  for (int k = 0; k < NCHUNK; ++k) {
    const int cur = k & 1;
    if (k < NCHUNK - 1) stage_load((k + 1) * CHUNK);
    if (comp) {
      const float* frb = smem + cur * FRELEMS;
      #pragma unroll
      for (int c2 = 0; c2 < 4; ++c2) {
        const int cc = cg * 4 + c2;
        const float* fp = frb + (cc * PR + dy) * PW + xg * 4;
        float w[16];
        #pragma unroll
        for (int j = 0; j < 4; ++j) {
          const float4 q4 = *(const float4*)(fp + 4 * j);
          w[4 * j] = q4.x; w[4 * j + 1] = q4.y; w[4 * j + 2] = q4.z; w[4 * j + 3] = q4.w;
        }
        const float4 tq = *(const float4*)(&ftbuf[cur][cc * TX + xg * 4]);
        const float tqa[4] = {tq.x, tq.y, tq.z, tq.w};
        #pragma unroll
        for (int dx = 0; dx < 13; ++dx)
          #pragma unroll
          for (int kk = 0; kk < 4; ++kk)
            acc[dx][kk] = fmaf(w[dx + kk], tqa[kk], acc[dx][kk]);
      }
    }
    // write(k+1) targets buf cur^1, last read by compute(k-1) — already
    // separated by the previous iteration's barrier. One barrier per chunk.
    if (k < NCHUNK - 1) stage_write(cur ^ 1);
    __syncthreads();
  }

  // --- cross-cg reduction (staging buffers dead now) ---
  if (comp && cg == 1) {
    float* rb = smem + tl * 52;
    #pragma unroll
    for (int dx = 0; dx < 13; ++dx)
      *(float4*)(rb + dx * 4) = make_float4(acc[dx][0], acc[dx][1], acc[dx][2], acc[dx][3]);
  }
  __syncthreads();
  if (comp && cg == 0) {
    const float* rb = smem + tl * 52;
    #pragma unroll
    for (int dx = 0; dx < 13; ++dx) {
      const float4 r = *(const float4*)(rb + dx * 4);
      acc[dx][0] += r.x; acc[dx][1] += r.y; acc[dx][2] += r.z; acc[dx][3] += r.w;
    }
  }
  __syncthreads();
  if (comp && cg == 0) {
    #pragma unroll
    for (int dx = 0; dx < 13; ++dx)
      #pragma unroll
      for (int kk = 0; kk < 4; ++kk)
        smem[(xg * 4 + kk) * NWIN + dy * 13 + dx] = acc[dx][kk];
  }
  __syncthreads();
  {
    float* gb = vol + ((size_t)(b * HW + y * W + x0) * 2 + ii) * NWIN;
    for (int u = 0; u < 22; ++u) {
      const int e = t + u * 256;
      if (e < TILE) {
        const int xl2 = e / NWIN;
        const int mm  = e - xl2 * NWIN;
        gb[(size_t)xl2 * (2 * NWIN) + mm] = smem[e];
      }
    }
  }
}

// ================= Kernel B: wave-per-pixel post-processing =================
__global__ __launch_bounds__(256) void post_kernel(
    const float* __restrict__ vol,  // [pix][2][169]
    const int*  __restrict__ lab,   // [4][64][64]
    float* __restrict__ out) {      // [2][32][64][64]
  const int blk  = blockIdx.x;
  const int t    = threadIdx.x;
  const int w    = t >> 6;
  const int lane = t & 63;
  const int pix  = blk * 4 + w;
  const int b = pix >> 12;
  const int y = (pix >> 6) & 63;
  const int x = pix & 63;

  __shared__ float accS[4][NCLS];
  accS[w][lane & 31] = 0.f;

  float vv[6];
  float lmax = -INFINITY;
  const float* vp = vol + (size_t)pix * NTOT;
  #pragma unroll
  for (int k = 0; k < 6; ++k) {
    const int e = lane + 64 * k;
    vv[k] = (e < NTOT) ? vp[e] : -INFINITY;
    lmax = fmaxf(lmax, vv[k]);
  }
  #pragma unroll
  for (int off = 32; off > 0; off >>= 1)
    lmax = fmaxf(lmax, __shfl_xor(lmax, off));

  float p[6];
  float lsum = 0.f;
  #pragma unroll
  for (int k = 0; k < 6; ++k) {
    const int e = lane + 64 * k;
    p[k] = (e < NTOT) ? __expf(vv[k] - lmax) : 0.f;
    lsum += p[k];
  }
  #pragma unroll
  for (int off = 32; off > 0; off >>= 1)
    lsum += __shfl_xor(lsum, off);
  const float rinv = 1.f / lsum;
  #pragma unroll
  for (int k = 0; k < 6; ++k) p[k] *= rinv;

  float a1_0 = -1.f, a2_0 = -1.f, a1_1 = -1.f, a2_1 = -1.f;
  int   j1_0 = 1 << 20, j2_0 = 1 << 20, j1_1 = 1 << 20, j2_1 = 1 << 20;
  #pragma unroll
  for (int k = 0; k < 6; ++k) {
    const int e = lane + 64 * k;
    if (e < NTOT) {
      const int r = (e >= NWIN) ? 1 : 0;
      const int m = e - r * NWIN;
      const float pv = p[k];
      if (r == 0) {
        if (better(pv, m, a1_0, j1_0)) { a2_0 = a1_0; j2_0 = j1_0; a1_0 = pv; j1_0 = m; }
        else if (better(pv, m, a2_0, j2_0)) { a2_0 = pv; j2_0 = m; }
      } else {
        if (better(pv, m, a1_1, j1_1)) { a2_1 = a1_1; j2_1 = j1_1; a1_1 = pv; j1_1 = m; }
        else if (better(pv, m, a2_1, j2_1)) { a2_1 = pv; j2_1 = m; }
      }
    }
  }
  #pragma unroll
  for (int off = 32; off > 0; off >>= 1) {
    {
      const float u1 = __shfl_xor(a1_0, off); const int q1 = __shfl_xor(j1_0, off);
      const float u2 = __shfl_xor(a2_0, off); const int q2 = __shfl_xor(j2_0, off);
      if (better(u1, q1, a1_0, j1_0)) {
        float nv2; int ni2;
        if (better(a1_0, j1_0, u2, q2)) { nv2 = a1_0; ni2 = j1_0; }
        else                            { nv2 = u2;   ni2 = q2; }
        a1_0 = u1; j1_0 = q1; a2_0 = nv2; j2_0 = ni2;
      } else if (better(u1, q1, a2_0, j2_0)) { a2_0 = u1; j2_0 = q1; }
    }
    {
      const float u1 = __shfl_xor(a1_1, off); const int q1 = __shfl_xor(j1_1, off);
      const float u2 = __shfl_xor(a2_1, off); const int q2 = __shfl_xor(j2_1, off);
      if (better(u1, q1, a1_1, j1_1)) {
        float nv2; int ni2;
        if (better(a1_1, j1_1, u2, q2)) { nv2 = a1_1; ni2 = j1_1; }
        else                            { nv2 = u2;   ni2 = q2; }
        a1_1 = u1; j1_1 = q1; a2_1 = nv2; j2_1 = ni2;
      } else if (better(u1, q1, a2_1, j2_1)) { a2_1 = u1; j2_1 = q1; }
    }
  }

  const float e10 = __expf(a1_0), e20 = __expf(a2_0);
  const float rs0 = 1.f / (e10 + e20);
  const float w00 = e10 * rs0, w10 = e20 * rs0;
  const bool  fl0 = (a1_0 > 0.1f);
  const float xs00 = (float)(j1_0 % P), ys00 = (float)(j1_0 / P);
  const float xs10 = (float)(j2_0 % P), ys10 = (float)(j2_0 / P);

  const float e11 = __expf(a1_1), e21 = __expf(a2_1);
  const float rs1 = 1.f / (e11 + e21);
  const float w01 = e11 * rs1, w11 = e21 * rs1;
  const bool  fl1 = (a1_1 > 0.1f);
  const float xs01 = (float)(j1_1 % P), ys01 = (float)(j1_1 / P);
  const float xs11 = (float)(j2_1 % P), ys11 = (float)(j2_1 / P);

  #pragma unroll
  for (int k = 0; k < 6; ++k) {
    const int e = lane + 64 * k;
    if (e < NTOT) {
      const int r  = (e >= NWIN) ? 1 : 0;
      const int m  = e - r * NWIN;
      const int dy = m / P;
      const int dx = m - dy * P;
      const bool  fl = r ? fl1 : fl0;
      float val;
      if (fl) {
        const float wA = r ? w01 : w00, wB = r ? w11 : w10;
        const float xA = r ? xs01 : xs00, yA = r ? ys01 : ys00;
        const float xB = r ? xs11 : xs10, yB = r ? ys11 : ys10;
        const float fdx0 = (float)dx - xA, fdy0 = (float)dy - yA;
        const float fdx1 = (float)dx - xB, fdy1 = (float)dy - yB;
        val = wA * __expf(-FOUR_LN2 * (fdx0 * fdx0 + fdy0 * fdy0))
            + wB * __expf(-FOUR_LN2 * (fdx1 * fdx1 + fdy1 * fdy1));
      } else {
        val = p[k];
      }
      const int yy = y + dy - RAD;
      const int xx = x + dx - RAD;
      if ((unsigned)yy < 64u && (unsigned)xx < 64u) {
        const int cls = lab[(size_t)(r * 2 + b) * 4096 + yy * W + xx];
        atomicAdd(&accS[w][cls], val);
      }
    }
  }
  __syncthreads();

  if (t < 4 * NCLS) {
    const int cls = t >> 2;
    const int j   = t & 3;
    const int x0  = (blk * 4) & 63;
    const float sc = (cls == 0) ? 1.0f : 1.15f;
    out[(size_t)(b * NCLS + cls) * HW + y * W + x0 + j] = accS[j][cls] * sc;
  }
}

}  // namespace

extern "C" void kernel_launch(void* const* d_in, const int* in_sizes, int n_in,
                              void* d_out, int out_size, void* d_ws, size_t ws_size,
                              hipStream_t stream) {
  const float* fr = (const float*)d_in[0];   // feats_r
  const float* ft = (const float*)d_in[1];   // feats_t
  const int*   q  = (const int*)d_in[2];     // quantized_r
  float* out = (float*)d_out;
  float* vol = (float*)d_ws;                                       // 11,075,584 B
  float* frp = (float*)((char*)d_ws + VOLF * sizeof(float));       // 12,451,840 B
  int*   lab = (int*)((char*)frp + (size_t)4 * NCH * PADCH * sizeof(float)); // 64 KB

  pad_kernel<<<dim3(3040), dim3(256), 0, stream>>>(fr, q, frp, lab);
  corr_kernel<<<dim3(2 * 2 * 64 * 2), dim3(256), 0, stream>>>(frp, ft, vol);
  post_kernel<<<dim3(2 * HW / 4), dim3(256), 0, stream>>>(vol, lab, out);
}

// Round 13
// 78.373 us; speedup vs baseline: 1.0802x; 1.0802x over previous
//
#include <hip/hip_runtime.h>
#include <math.h>

namespace {

constexpr int RAD  = 6;
constexpr int P    = 13;
constexpr int NWIN = 169;   // P*P
constexpr int NTOT = 338;   // 2 refs * NWIN
constexpr int NCH  = 128;
constexpr int NCLS = 32;
constexpr int W    = 64;
constexpr int HW   = 4096;
constexpr float FOUR_LN2 = 2.772588722239781f;

// ---- kernel A tiling (R9-proven geometry & traffic) ----
constexpr int TX    = 32;            // pixels per block (half row)
constexpr int CHUNK = 8;             // channels per stage
constexpr int PW    = 48;            // patch width: 44 used + 4 pad
constexpr int PR    = 13;            // patch rows (dy)
constexpr int FRELEMS = CHUNK * PR * PW;   // 4992
constexpr int NLD   = 20;            // ceil(4992/256)
constexpr int NCHUNK = NCH / CHUNK;  // 16
constexpr int TILE  = TX * NWIN;     // 5408 floats
constexpr size_t VOLF = (size_t)2 * HW * NTOT;  // floats in volume

__device__ __forceinline__ bool better(float va, int ia, float vb, int ib) {
  return (va > vb) || ((va == vb) && (ia < ib));
}

// ================= Kernel A: correlation volume =================
// grid: ((b*2+i)*64 + y)*2 + xh   (512 blocks), 256 threads
// R9 dataflow + 2-deep load pipeline (two reg sets), 1 barrier per chunk.
__global__ __launch_bounds__(256, 2) void corr_kernel(
    const float* __restrict__ fr,   // [2][2][128][64][64]  (nref,b,c,y,x)
    const float* __restrict__ ft,   // [2][128][64][64]
    float* __restrict__ vol) {
  const int blk = blockIdx.x;
  const int xh = blk & 1;
  const int y  = (blk >> 1) & 63;
  const int bi = blk >> 7;             // b*2+i
  const int b  = bi >> 1;
  const int ii = bi & 1;
  const int x0 = xh * TX;
  const int t  = threadIdx.x;
  const int cg = t >> 7;               // channel group 0/1
  const int tl = t & 127;

  __shared__ __align__(16) float smem[2 * FRELEMS];     // 39936 B
  __shared__ __align__(16) float ftbuf[2][CHUNK * TX];  // 2048 B

  const int xg = tl & 7;               // x-quad within half row
  const int dy = tl >> 3;              // 0..12 valid when tl<104
  const bool comp = (tl < 104);

  // fr outer layout is [nref][b] -> index ii*2+b
  const float* frbase = fr + (size_t)((ii * 2 + b) * NCH) * HW;
  const float* ftp = ft + (size_t)(b * NCH + (t >> 5)) * HW + y * W + x0 + (t & 31);

  // ---- hoisted staging offsets (loop-invariant across chunks) ----
  int offc[NLD];
  unsigned vmsk = 0u;
  #pragma unroll
  for (int u = 0; u < NLD; ++u) {
    const int e = t + u * 256;
    int o = 0;
    if (e < FRELEMS) {
      const int cc  = e / (PR * PW);
      const int rem = e - cc * (PR * PW);
      const int r   = rem / PW;
      const int xc  = rem - r * PW;
      const int yy  = y + r - RAD;
      const int xx  = x0 - RAD + xc;
      if ((unsigned)yy < 64u && (unsigned)xx < 64u && xc < 44) {
        o = cc * HW + yy * W + xx;
        vmsk |= (1u << u);
      }
    }
    offc[u] = o;
  }

  float acc[13][4];
  #pragma unroll
  for (int dx = 0; dx < 13; ++dx)
    #pragma unroll
    for (int k = 0; k < 4; ++k) acc[dx][k] = 0.f;

  float rgA[NLD], rgB[NLD];
  float rftA, rftB;

  auto stage_load = [&](int c0, float (&rg)[NLD], float& rft) {
    const float* fb = frbase + (size_t)c0 * HW;
    #pragma unroll
    for (int u = 0; u < NLD; ++u) {
      const float v = fb[offc[u]];
      rg[u] = (vmsk & (1u << u)) ? v : 0.f;
    }
    rft = ftp[(size_t)c0 * HW];
  };
  auto stage_write = [&](int s, const float (&rg)[NLD], float rft) {
    float* frb = smem + s * FRELEMS;
    #pragma unroll
    for (int u = 0; u < NLD; ++u) {
      const int e = t + u * 256;
      if (e < FRELEMS) frb[e] = rg[u];
    }
    ftbuf[s][t] = rft;
  };

  // prologue: chunk0 staged; chunk1 loads in flight across the barrier
  stage_load(0, rgA, rftA);
  stage_write(0, rgA, rftA);
  stage_load(CHUNK, rgB, rftB);
  __syncthreads();

  for (int k = 0; k < NCHUNK; ++k) {
    const int cur = k & 1;
    // issue loads for chunk k+2 into the regset freed at iter k-1
    if (k < NCHUNK - 2) {
      if (k & 1) stage_load((k + 2) * CHUNK, rgB, rftB);
      else       stage_load((k + 2) * CHUNK, rgA, rftA);
    }
    if (comp) {
      const float* frb = smem + cur * FRELEMS;
      #pragma unroll
      for (int c2 = 0; c2 < 4; ++c2) {
        const int cc = cg * 4 + c2;
        const float* fp = frb + (cc * PR + dy) * PW + xg * 4;
        float w[16];
        #pragma unroll
        for (int j = 0; j < 4; ++j) {
          const float4 q4 = *(const float4*)(fp + 4 * j);
          w[4 * j] = q4.x; w[4 * j + 1] = q4.y; w[4 * j + 2] = q4.z; w[4 * j + 3] = q4.w;
        }
        const float4 tq = *(const float4*)(&ftbuf[cur][cc * TX + xg * 4]);
        const float tqa[4] = {tq.x, tq.y, tq.z, tq.w};
        #pragma unroll
        for (int dx = 0; dx < 13; ++dx)
          #pragma unroll
          for (int kk = 0; kk < 4; ++kk)
            acc[dx][kk] = fmaf(w[dx + kk], tqa[kk], acc[dx][kk]);
      }
    }
    // write chunk k+1 (loads issued at iter k-1 -> ~2 chunk-periods of cover)
    // into buf cur^1: compute(k) reads buf cur; compute(k-1)'s readers of
    // buf cur^1 are separated by the iter k-1 barrier. Race-checked.
    if (k < NCHUNK - 1) {
      if (k & 1) stage_write(cur ^ 1, rgA, rftA);
      else       stage_write(cur ^ 1, rgB, rftB);
    }
    __syncthreads();
  }

  // --- cross-cg reduction (staging buffers dead now) ---
  if (comp && cg == 1) {
    float* rb = smem + tl * 52;
    #pragma unroll
    for (int dx = 0; dx < 13; ++dx)
      *(float4*)(rb + dx * 4) = make_float4(acc[dx][0], acc[dx][1], acc[dx][2], acc[dx][3]);
  }
  __syncthreads();
  if (comp && cg == 0) {
    const float* rb = smem + tl * 52;
    #pragma unroll
    for (int dx = 0; dx < 13; ++dx) {
      const float4 r = *(const float4*)(rb + dx * 4);
      acc[dx][0] += r.x; acc[dx][1] += r.y; acc[dx][2] += r.z; acc[dx][3] += r.w;
    }
  }
  __syncthreads();
  if (comp && cg == 0) {
    #pragma unroll
    for (int dx = 0; dx < 13; ++dx)
      #pragma unroll
      for (int kk = 0; kk < 4; ++kk)
        smem[(xg * 4 + kk) * NWIN + dy * 13 + dx] = acc[dx][kk];
  }
  __syncthreads();
  {
    float* gb = vol + ((size_t)(b * HW + y * W + x0) * 2 + ii) * NWIN;
    for (int u = 0; u < 22; ++u) {
      const int e = t + u * 256;
      if (e < TILE) {
        const int xl2 = e / NWIN;
        const int mm  = e - xl2 * NWIN;
        gb[(size_t)xl2 * (2 * NWIN) + mm] = smem[e];
      }
    }
  }
}

// ================= Kernel L: dense down-sampled label map =================
__global__ __launch_bounds__(256) void lab_kernel(
    const int* __restrict__ q, int* __restrict__ lab) {
  const int idx = blockIdx.x * 256 + threadIdx.x;   // 0..16383
  const int i2b = idx >> 12;
  const int rem = idx & 4095;
  const int yy  = rem >> 6;
  const int xx  = rem & 63;
  lab[idx] = q[(size_t)i2b * 65536 + (yy * 4) * 256 + xx * 4];
}

// ================= Kernel B: wave-per-pixel post-processing =================
__global__ __launch_bounds__(256) void post_kernel(
    const float* __restrict__ vol,  // [pix][2][169]
    const int*  __restrict__ lab,   // [4][64][64]
    float* __restrict__ out) {      // [2][32][64][64]
  const int blk  = blockIdx.x;
  const int t    = threadIdx.x;
  const int w    = t >> 6;
  const int lane = t & 63;
  const int pix  = blk * 4 + w;
  const int b = pix >> 12;
  const int y = (pix >> 6) & 63;
  const int x = pix & 63;

  __shared__ float accS[4][NCLS];
  accS[w][lane & 31] = 0.f;

  float vv[6];
  float lmax = -INFINITY;
  const float* vp = vol + (size_t)pix * NTOT;
  #pragma unroll
  for (int k = 0; k < 6; ++k) {
    const int e = lane + 64 * k;
    vv[k] = (e < NTOT) ? vp[e] : -INFINITY;
    lmax = fmaxf(lmax, vv[k]);
  }
  #pragma unroll
  for (int off = 32; off > 0; off >>= 1)
    lmax = fmaxf(lmax, __shfl_xor(lmax, off));

  float p[6];
  float lsum = 0.f;
  #pragma unroll
  for (int k = 0; k < 6; ++k) {
    const int e = lane + 64 * k;
    p[k] = (e < NTOT) ? __expf(vv[k] - lmax) : 0.f;
    lsum += p[k];
  }
  #pragma unroll
  for (int off = 32; off > 0; off >>= 1)
    lsum += __shfl_xor(lsum, off);
  const float rinv = 1.f / lsum;
  #pragma unroll
  for (int k = 0; k < 6; ++k) p[k] *= rinv;

  float a1_0 = -1.f, a2_0 = -1.f, a1_1 = -1.f, a2_1 = -1.f;
  int   j1_0 = 1 << 20, j2_0 = 1 << 20, j1_1 = 1 << 20, j2_1 = 1 << 20;
  #pragma unroll
  for (int k = 0; k < 6; ++k) {
    const int e = lane + 64 * k;
    if (e < NTOT) {
      const int r = (e >= NWIN) ? 1 : 0;
      const int m = e - r * NWIN;
      const float pv = p[k];
      if (r == 0) {
        if (better(pv, m, a1_0, j1_0)) { a2_0 = a1_0; j2_0 = j1_0; a1_0 = pv; j1_0 = m; }
        else if (better(pv, m, a2_0, j2_0)) { a2_0 = pv; j2_0 = m; }
      } else {
        if (better(pv, m, a1_1, j1_1)) { a2_1 = a1_1; j2_1 = j1_1; a1_1 = pv; j1_1 = m; }
        else if (better(pv, m, a2_1, j2_1)) { a2_1 = pv; j2_1 = m; }
      }
    }
  }
  #pragma unroll
  for (int off = 32; off > 0; off >>= 1) {
    {
      const float u1 = __shfl_xor(a1_0, off); const int q1 = __shfl_xor(j1_0, off);
      const float u2 = __shfl_xor(a2_0, off); const int q2 = __shfl_xor(j2_0, off);
      if (better(u1, q1, a1_0, j1_0)) {
        float nv2; int ni2;
        if (better(a1_0, j1_0, u2, q2)) { nv2 = a1_0; ni2 = j1_0; }
        else                            { nv2 = u2;   ni2 = q2; }
        a1_0 = u1; j1_0 = q1; a2_0 = nv2; j2_0 = ni2;
      } else if (better(u1, q1, a2_0, j2_0)) { a2_0 = u1; j2_0 = q1; }
    }
    {
      const float u1 = __shfl_xor(a1_1, off); const int q1 = __shfl_xor(j1_1, off);
      const float u2 = __shfl_xor(a2_1, off); const int q2 = __shfl_xor(j2_1, off);
      if (better(u1, q1, a1_1, j1_1)) {
        float nv2; int ni2;
        if (better(a1_1, j1_1, u2, q2)) { nv2 = a1_1; ni2 = j1_1; }
        else                            { nv2 = u2;   ni2 = q2; }
        a1_1 = u1; j1_1 = q1; a2_1 = nv2; j2_1 = ni2;
      } else if (better(u1, q1, a2_1, j2_1)) { a2_1 = u1; j2_1 = q1; }
    }
  }

  const float e10 = __expf(a1_0), e20 = __expf(a2_0);
  const float rs0 = 1.f / (e10 + e20);
  const float w00 = e10 * rs0, w10 = e20 * rs0;
  const bool  fl0 = (a1_0 > 0.1f);
  const float xs00 = (float)(j1_0 % P), ys00 = (float)(j1_0 / P);
  const float xs10 = (float)(j2_0 % P), ys10 = (float)(j2_0 / P);

  const float e11 = __expf(a1_1), e21 = __expf(a2_1);
  const float rs1 = 1.f / (e11 + e21);
  const float w01 = e11 * rs1, w11 = e21 * rs1;
  const bool  fl1 = (a1_1 > 0.1f);
  const float xs01 = (float)(j1_1 % P), ys01 = (float)(j1_1 / P);
  const float xs11 = (float)(j2_1 % P), ys11 = (float)(j2_1 / P);

  #pragma unroll
  for (int k = 0; k < 6; ++k) {
    const int e = lane + 64 * k;
    if (e < NTOT) {
      const int r  = (e >= NWIN) ? 1 : 0;
      const int m  = e - r * NWIN;
      const int dy = m / P;
      const int dx = m - dy * P;
      const bool  fl = r ? fl1 : fl0;
      float val;
      if (fl) {
        const float wA = r ? w01 : w00, wB = r ? w11 : w10;
        const float xA = r ? xs01 : xs00, yA = r ? ys01 : ys00;
        const float xB = r ? xs11 : xs10, yB = r ? ys11 : ys10;
        const float fdx0 = (float)dx - xA, fdy0 = (float)dy - yA;
        const float fdx1 = (float)dx - xB, fdy1 = (float)dy - yB;
        val = wA * __expf(-FOUR_LN2 * (fdx0 * fdx0 + fdy0 * fdy0))
            + wB * __expf(-FOUR_LN2 * (fdx1 * fdx1 + fdy1 * fdy1));
      } else {
        val = p[k];
      }
      const int yy = y + dy - RAD;
      const int xx = x + dx - RAD;
      if ((unsigned)yy < 64u && (unsigned)xx < 64u) {
        const int cls = lab[(size_t)(r * 2 + b) * 4096 + yy * W + xx];
        atomicAdd(&accS[w][cls], val);
      }
    }
  }
  __syncthreads();

  if (t < 4 * NCLS) {
    const int cls = t >> 2;
    const int j   = t & 3;
    const int x0  = (blk * 4) & 63;
    const float sc = (cls == 0) ? 1.0f : 1.15f;
    out[(size_t)(b * NCLS + cls) * HW + y * W + x0 + j] = accS[j][cls] * sc;
  }
}

}  // namespace

extern "C" void kernel_launch(void* const* d_in, const int* in_sizes, int n_in,
                              void* d_out, int out_size, void* d_ws, size_t ws_size,
                              hipStream_t stream) {
  const float* fr = (const float*)d_in[0];   // feats_r
  const float* ft = (const float*)d_in[1];   // feats_t
  const int*   q  = (const int*)d_in[2];     // quantized_r
  float* out = (float*)d_out;
  float* vol = (float*)d_ws;                                   // 11,075,584 B
  int*   lab = (int*)((char*)d_ws + VOLF * sizeof(float));     // +64 KB

  lab_kernel<<<dim3(64), dim3(256), 0, stream>>>(q, lab);
  corr_kernel<<<dim3(2 * 2 * 64 * 2), dim3(256), 0, stream>>>(fr, ft, vol);
  post_kernel<<<dim3(2 * HW / 4), dim3(256), 0, stream>>>(vol, lab, out);
}

// Round 14
// 63.147 us; speedup vs baseline: 1.3407x; 1.2411x over previous
//
#include <hip/hip_runtime.h>
#include <math.h>

namespace {

constexpr int RAD  = 6;
constexpr int P    = 13;
constexpr int NWIN = 169;   // P*P
constexpr int NTOT = 338;   // 2 refs * NWIN
constexpr int NCH  = 128;
constexpr int NCLS = 32;
constexpr int W    = 64;
constexpr int HW   = 4096;
constexpr float FOUR_LN2 = 2.772588722239781f;

// ---- tiling (R9-proven geometry & traffic) ----
constexpr int TX    = 32;            // pixels per block (half row)
constexpr int CHUNK = 8;             // channels per stage
constexpr int PW    = 48;            // patch width: 44 used + 4 pad
constexpr int PR    = 13;            // patch rows (dy)
constexpr int FRELEMS = CHUNK * PR * PW;   // 4992
constexpr int NLD   = 20;            // ceil(4992/256)
constexpr int NCHUNK = NCH / CHUNK;  // 16

__device__ __forceinline__ bool better(float va, int ia, float vb, int ib) {
  return (va > vb) || ((va == vb) && (ia < ib));
}

// ================= Kernel L: dense down-sampled label map =================
__global__ __launch_bounds__(256) void lab_kernel(
    const int* __restrict__ q, int* __restrict__ lab) {
  const int idx = blockIdx.x * 256 + threadIdx.x;   // 0..16383
  const int i2b = idx >> 12;
  const int rem = idx & 4095;
  const int yy  = rem >> 6;
  const int xx  = rem & 63;
  lab[idx] = q[(size_t)i2b * 65536 + (yy * 4) * 256 + xx * 4];
}

// ================= Fused kernel: corr + softmax + top2 + heat + scatter ====
// grid: b*128 + y*2 + xh  (256 blocks), 512 threads (8 waves).
// Threads [0,256): ref 0; [256,512): ref 1. Each half = R9's corr pipeline.
__global__ __launch_bounds__(512, 2) void fused_kernel(
    const float* __restrict__ fr,   // [2][2][128][64][64]  (nref,b,c,y,x)
    const float* __restrict__ ft,   // [2][128][64][64]
    const int*  __restrict__ lab,   // [4][64][64]
    float* __restrict__ out) {      // [2][32][64][64]
  const int blk = blockIdx.x;
  const int xh = blk & 1;
  const int y  = (blk >> 1) & 63;
  const int b  = blk >> 7;
  const int x0 = xh * TX;
  const int t  = threadIdx.x;
  const int ii = t >> 8;               // ref handled by this thread-half
  const int tt = t & 255;
  const int cg = tt >> 7;              // channel group 0/1 within half
  const int tl = tt & 127;

  __shared__ __align__(16) float smem[4 * FRELEMS];     // [ref][buf][4992] = 79872 B
  __shared__ __align__(16) float ftbuf[2][CHUNK * TX];  // 2048 B (shared by refs)
  __shared__ float accS[TX][NCLS];                      // 4096 B

  const int xg = tl & 7;               // x-quad within half row
  const int dy = tl >> 3;              // 0..12 valid when tl<104
  const bool comp = (tl < 104);

  float* stg = smem + ii * (2 * FRELEMS);
  // fr outer layout is [nref][b] -> index ii*2+b
  const float* frbase = fr + (size_t)((ii * 2 + b) * NCH) * HW;
  const float* ftp = ft + (size_t)(b * NCH + (tt >> 5)) * HW + y * W + x0 + (tt & 31);

  // ---- hoisted staging offsets (loop-invariant across chunks) ----
  int offc[NLD];
  unsigned vmsk = 0u;
  #pragma unroll
  for (int u = 0; u < NLD; ++u) {
    const int e = tt + u * 256;
    int o = 0;
    if (e < FRELEMS) {
      const int cc  = e / (PR * PW);
      const int rem = e - cc * (PR * PW);
      const int r   = rem / PW;
      const int xc  = rem - r * PW;
      const int yy  = y + r - RAD;
      const int xx  = x0 - RAD + xc;
      if ((unsigned)yy < 64u && (unsigned)xx < 64u && xc < 44) {
        o = cc * HW + yy * W + xx;
        vmsk |= (1u << u);
      }
    }
    offc[u] = o;
  }

  float acc[13][4];
  #pragma unroll
  for (int dx = 0; dx < 13; ++dx)
    #pragma unroll
    for (int k = 0; k < 4; ++k) acc[dx][k] = 0.f;

  float rg[NLD];
  float rft;

  auto stage_load = [&](int c0) {
    const float* fb = frbase + (size_t)c0 * HW;
    #pragma unroll
    for (int u = 0; u < NLD; ++u) {
      const float v = fb[offc[u]];
      rg[u] = (vmsk & (1u << u)) ? v : 0.f;
    }
    if (t < 256) rft = ftp[(size_t)c0 * HW];    // ft staged once (ref-0 half)
  };
  auto stage_write = [&](int s) {
    float* frb = stg + s * FRELEMS;
    #pragma unroll
    for (int u = 0; u < NLD; ++u) {
      const int e = tt + u * 256;
      if (e < FRELEMS) frb[e] = rg[u];
    }
    if (t < 256) ftbuf[s][tt] = rft;
  };

  stage_load(0);
  stage_write(0);
  __syncthreads();

  for (int k = 0; k < NCHUNK; ++k) {
    const int cur = k & 1;
    if (k < NCHUNK - 1) stage_load((k + 1) * CHUNK);
    if (comp) {
      const float* frb = stg + cur * FRELEMS;
      #pragma unroll
      for (int c2 = 0; c2 < 4; ++c2) {
        const int cc = cg * 4 + c2;
        const float* fp = frb + (cc * PR + dy) * PW + xg * 4;
        float w[16];
        #pragma unroll
        for (int j = 0; j < 4; ++j) {
          const float4 q4 = *(const float4*)(fp + 4 * j);
          w[4 * j] = q4.x; w[4 * j + 1] = q4.y; w[4 * j + 2] = q4.z; w[4 * j + 3] = q4.w;
        }
        const float4 tq = *(const float4*)(&ftbuf[cur][cc * TX + xg * 4]);
        const float tqa[4] = {tq.x, tq.y, tq.z, tq.w};
        #pragma unroll
        for (int dx = 0; dx < 13; ++dx)
          #pragma unroll
          for (int kk = 0; kk < 4; ++kk)
            acc[dx][kk] = fmaf(w[dx + kk], tqa[kk], acc[dx][kk]);
      }
    }
    // write(k) targets buf cur^1, last read by compute(k-1): separated by
    // the previous iteration's barrier (R9-proven single-barrier schedule).
    if (k < NCHUNK - 1) stage_write(cur ^ 1);
    __syncthreads();
  }

  // ---- tile build: staging LDS is dead; overlay tile[32][338] at smem[0) ----
  float* tile = smem;
  if (comp && cg == 1) {
    #pragma unroll
    for (int dx = 0; dx < 13; ++dx)
      #pragma unroll
      for (int kk = 0; kk < 4; ++kk)
        tile[(xg * 4 + kk) * NTOT + ii * NWIN + dy * 13 + dx] = acc[dx][kk];
  }
  ((float*)accS)[t] = 0.f;
  ((float*)accS)[t + 512] = 0.f;
  __syncthreads();
  if (comp && cg == 0) {
    #pragma unroll
    for (int dx = 0; dx < 13; ++dx)
      #pragma unroll
      for (int kk = 0; kk < 4; ++kk) {
        const int idx = (xg * 4 + kk) * NTOT + ii * NWIN + dy * 13 + dx;
        tile[idx] += acc[dx][kk];
      }
  }
  __syncthreads();

  // ---- post: 8 waves x 4 pixels, R8-proven wave-per-pixel logic from LDS ----
  const int wv   = t >> 6;
  const int lane = t & 63;
  for (int j = 0; j < 4; ++j) {
    const int px = (wv << 2) | j;
    const int x  = x0 + px;
    const float* tp = tile + (size_t)px * NTOT;

    float vv[6];
    float lmax = -INFINITY;
    #pragma unroll
    for (int k = 0; k < 6; ++k) {
      const int e = lane + 64 * k;
      vv[k] = (e < NTOT) ? tp[e] : -INFINITY;
      lmax = fmaxf(lmax, vv[k]);
    }
    #pragma unroll
    for (int off = 32; off > 0; off >>= 1)
      lmax = fmaxf(lmax, __shfl_xor(lmax, off));

    float p[6];
    float lsum = 0.f;
    #pragma unroll
    for (int k = 0; k < 6; ++k) {
      const int e = lane + 64 * k;
      p[k] = (e < NTOT) ? __expf(vv[k] - lmax) : 0.f;
      lsum += p[k];
    }
    #pragma unroll
    for (int off = 32; off > 0; off >>= 1)
      lsum += __shfl_xor(lsum, off);
    const float rinv = 1.f / lsum;
    #pragma unroll
    for (int k = 0; k < 6; ++k) p[k] *= rinv;

    float a1_0 = -1.f, a2_0 = -1.f, a1_1 = -1.f, a2_1 = -1.f;
    int   j1_0 = 1 << 20, j2_0 = 1 << 20, j1_1 = 1 << 20, j2_1 = 1 << 20;
    #pragma unroll
    for (int k = 0; k < 6; ++k) {
      const int e = lane + 64 * k;
      if (e < NTOT) {
        const int r = (e >= NWIN) ? 1 : 0;
        const int m = e - r * NWIN;
        const float pv = p[k];
        if (r == 0) {
          if (better(pv, m, a1_0, j1_0)) { a2_0 = a1_0; j2_0 = j1_0; a1_0 = pv; j1_0 = m; }
          else if (better(pv, m, a2_0, j2_0)) { a2_0 = pv; j2_0 = m; }
        } else {
          if (better(pv, m, a1_1, j1_1)) { a2_1 = a1_1; j2_1 = j1_1; a1_1 = pv; j1_1 = m; }
          else if (better(pv, m, a2_1, j2_1)) { a2_1 = pv; j2_1 = m; }
        }
      }
    }
    #pragma unroll
    for (int off = 32; off > 0; off >>= 1) {
      {
        const float u1 = __shfl_xor(a1_0, off); const int q1 = __shfl_xor(j1_0, off);
        const float u2 = __shfl_xor(a2_0, off); const int q2 = __shfl_xor(j2_0, off);
        if (better(u1, q1, a1_0, j1_0)) {
          float nv2; int ni2;
          if (better(a1_0, j1_0, u2, q2)) { nv2 = a1_0; ni2 = j1_0; }
          else                            { nv2 = u2;   ni2 = q2; }
          a1_0 = u1; j1_0 = q1; a2_0 = nv2; j2_0 = ni2;
        } else if (better(u1, q1, a2_0, j2_0)) { a2_0 = u1; j2_0 = q1; }
      }
      {
        const float u1 = __shfl_xor(a1_1, off); const int q1 = __shfl_xor(j1_1, off);
        const float u2 = __shfl_xor(a2_1, off); const int q2 = __shfl_xor(j2_1, off);
        if (better(u1, q1, a1_1, j1_1)) {
          float nv2; int ni2;
          if (better(a1_1, j1_1, u2, q2)) { nv2 = a1_1; ni2 = j1_1; }
          else                            { nv2 = u2;   ni2 = q2; }
          a1_1 = u1; j1_1 = q1; a2_1 = nv2; j2_1 = ni2;
        } else if (better(u1, q1, a2_1, j2_1)) { a2_1 = u1; j2_1 = q1; }
      }
    }

    const float e10 = __expf(a1_0), e20 = __expf(a2_0);
    const float rs0 = 1.f / (e10 + e20);
    const float w00 = e10 * rs0, w10 = e20 * rs0;
    const bool  fl0 = (a1_0 > 0.1f);
    const float xs00 = (float)(j1_0 % P), ys00 = (float)(j1_0 / P);
    const float xs10 = (float)(j2_0 % P), ys10 = (float)(j2_0 / P);

    const float e11 = __expf(a1_1), e21 = __expf(a2_1);
    const float rs1 = 1.f / (e11 + e21);
    const float w01 = e11 * rs1, w11 = e21 * rs1;
    const bool  fl1 = (a1_1 > 0.1f);
    const float xs01 = (float)(j1_1 % P), ys01 = (float)(j1_1 / P);
    const float xs11 = (float)(j2_1 % P), ys11 = (float)(j2_1 / P);

    #pragma unroll
    for (int k = 0; k < 6; ++k) {
      const int e = lane + 64 * k;
      if (e < NTOT) {
        const int r   = (e >= NWIN) ? 1 : 0;
        const int m   = e - r * NWIN;
        const int dy2 = m / P;
        const int dx2 = m - dy2 * P;
        const bool fl = r ? fl1 : fl0;
        float val;
        if (fl) {
          const float wA = r ? w01 : w00, wB = r ? w11 : w10;
          const float xA = r ? xs01 : xs00, yA = r ? ys01 : ys00;
          const float xB = r ? xs11 : xs10, yB = r ? ys11 : ys10;
          const float fdx0 = (float)dx2 - xA, fdy0 = (float)dy2 - yA;
          const float fdx1 = (float)dx2 - xB, fdy1 = (float)dy2 - yB;
          val = wA * __expf(-FOUR_LN2 * (fdx0 * fdx0 + fdy0 * fdy0))
              + wB * __expf(-FOUR_LN2 * (fdx1 * fdx1 + fdy1 * fdy1));
        } else {
          val = p[k];
        }
        const int yy = y + dy2 - RAD;
        const int xx = x + dx2 - RAD;
        if ((unsigned)yy < 64u && (unsigned)xx < 64u) {
          const int cls = lab[(size_t)(r * 2 + b) * 4096 + yy * W + xx];
          atomicAdd(&accS[px][cls], val);
        }
      }
    }
  }
  __syncthreads();

  // ---- output: 1024 values, coalesced 32-float runs per class ----
  #pragma unroll
  for (int o = t; o < TX * NCLS; o += 512) {
    const int cls = o >> 5;
    const int px  = o & 31;
    const float sc = (cls == 0) ? 1.0f : 1.15f;
    out[(size_t)(b * NCLS + cls) * HW + y * W + x0 + px] = accS[px][cls] * sc;
  }
}

}  // namespace

extern "C" void kernel_launch(void* const* d_in, const int* in_sizes, int n_in,
                              void* d_out, int out_size, void* d_ws, size_t ws_size,
                              hipStream_t stream) {
  const float* fr = (const float*)d_in[0];   // feats_r
  const float* ft = (const float*)d_in[1];   // feats_t
  const int*   q  = (const int*)d_in[2];     // quantized_r
  float* out = (float*)d_out;
  int*   lab = (int*)d_ws;                   // 64 KB (vol eliminated)

  lab_kernel<<<dim3(64), dim3(256), 0, stream>>>(q, lab);
  fused_kernel<<<dim3(2 * 64 * 2), dim3(512), 0, stream>>>(fr, ft, lab, out);
}

// Round 15
// 58.676 us; speedup vs baseline: 1.4429x; 1.0762x over previous
//
#include <hip/hip_runtime.h>
#include <math.h>

namespace {

constexpr int RAD  = 6;
constexpr int P    = 13;
constexpr int NWIN = 169;   // P*P
constexpr int NTOT = 338;   // 2 refs * NWIN
constexpr int NCH  = 128;
constexpr int NCLS = 32;
constexpr int W    = 64;
constexpr int HW   = 4096;
constexpr float FOUR_LN2 = 2.772588722239781f;

// ---- kernel A tiling (R9-proven geometry & traffic) ----
constexpr int TX    = 32;            // pixels per block (half row)
constexpr int CHUNK = 8;             // channels per stage
constexpr int PW    = 48;            // patch width: 44 used + 4 pad
constexpr int PR    = 13;            // patch rows (dy)
constexpr int FRELEMS = CHUNK * PR * PW;   // 4992
constexpr int NLD   = 20;            // ceil(4992/256)
constexpr int NCHUNK = NCH / CHUNK;  // 16
constexpr int TILE  = TX * NWIN;     // 5408 floats
constexpr size_t VOLF = (size_t)2 * HW * NTOT;  // floats in volume

__device__ __forceinline__ bool better(float va, int ia, float vb, int ib) {
  return (va > vb) || ((va == vb) && (ia < ib));
}

// ================= Kernel A: correlation volume =================
// 512 blocks, 256 threads. XCD-aware swizzle: XCD k (= blk%8, round-robin
// dispatch) gets the contiguous logical slice [k*64,(k+1)*64) = one (ref,b)
// tensor x half the y range -> fr working set ~1.4MB fits the 4MB XCD L2.
// First 64 blocks also build the label map (folded lab_kernel).
__global__ __launch_bounds__(256, 2) void corr_kernel(
    const float* __restrict__ fr,   // [2][2][128][64][64]  (nref,b,c,y,x)
    const float* __restrict__ ft,   // [2][128][64][64]
    float* __restrict__ vol,
    const int* __restrict__ q,
    int* __restrict__ lab) {
  const int blk = blockIdx.x;
  const int t  = threadIdx.x;

  // ---- folded label map (64 blocks x 256 threads = 16384 elements) ----
  if (blk < 64) {
    const int idx = blk * 256 + t;
    const int i2b = idx >> 12;
    const int rem = idx & 4095;
    const int y2  = rem >> 6;
    const int x2  = rem & 63;
    lab[idx] = q[(size_t)i2b * 65536 + (y2 * 4) * 256 + x2 * 4];
  }

  // ---- XCD-locality swizzle (bijective: 512 = 8 * 64) ----
  const int lb = (blk & 7) * 64 + (blk >> 3);
  const int xh = lb & 1;
  const int y  = (lb >> 1) & 63;
  const int bi = lb >> 7;              // b*2+i
  const int b  = bi >> 1;
  const int ii = bi & 1;
  const int x0 = xh * TX;
  const int cg = t >> 7;               // channel group 0/1
  const int tl = t & 127;

  __shared__ __align__(16) float smem[2 * FRELEMS];     // 39936 B
  __shared__ __align__(16) float ftbuf[2][CHUNK * TX];  // 2048 B

  const int xg = tl & 7;               // x-quad within half row
  const int dy = tl >> 3;              // 0..12 valid when tl<104
  const bool comp = (tl < 104);

  // fr outer layout is [nref][b] -> index ii*2+b
  const float* frbase = fr + (size_t)((ii * 2 + b) * NCH) * HW;
  const float* ftp = ft + (size_t)(b * NCH + (t >> 5)) * HW + y * W + x0 + (t & 31);

  // ---- hoisted staging offsets (loop-invariant across chunks) ----
  int offc[NLD];
  unsigned vmsk = 0u;
  #pragma unroll
  for (int u = 0; u < NLD; ++u) {
    const int e = t + u * 256;
    int o = 0;
    if (e < FRELEMS) {
      const int cc  = e / (PR * PW);
      const int rem = e - cc * (PR * PW);
      const int r   = rem / PW;
      const int xc  = rem - r * PW;
      const int yy  = y + r - RAD;
      const int xx  = x0 - RAD + xc;
      if ((unsigned)yy < 64u && (unsigned)xx < 64u && xc < 44) {
        o = cc * HW + yy * W + xx;
        vmsk |= (1u << u);
      }
    }
    offc[u] = o;
  }

  float acc[13][4];
  #pragma unroll
  for (int dx = 0; dx < 13; ++dx)
    #pragma unroll
    for (int k = 0; k < 4; ++k) acc[dx][k] = 0.f;

  float rg[NLD];
  float rft;

  auto stage_load = [&](int c0) {
    const float* fb = frbase + (size_t)c0 * HW;
    #pragma unroll
    for (int u = 0; u < NLD; ++u) {
      const float v = fb[offc[u]];
      rg[u] = (vmsk & (1u << u)) ? v : 0.f;
    }
    rft = ftp[(size_t)c0 * HW];
  };
  auto stage_write = [&](int s) {
    float* frb = smem + s * FRELEMS;
    #pragma unroll
    for (int u = 0; u < NLD; ++u) {
      const int e = t + u * 256;
      if (e < FRELEMS) frb[e] = rg[u];
    }
    ftbuf[s][t] = rft;
  };

  stage_load(0);
  stage_write(0);
  __syncthreads();

  for (int k = 0; k < NCHUNK; ++k) {
    const int cur = k & 1;
    if (k < NCHUNK - 1) stage_load((k + 1) * CHUNK);
    if (comp) {
      const float* frb = smem + cur * FRELEMS;
      #pragma unroll
      for (int c2 = 0; c2 < 4; ++c2) {
        const int cc = cg * 4 + c2;
        const float* fp = frb + (cc * PR + dy) * PW + xg * 4;
        float w[16];
        #pragma unroll
        for (int j = 0; j < 4; ++j) {
          const float4 q4 = *(const float4*)(fp + 4 * j);
          w[4 * j] = q4.x; w[4 * j + 1] = q4.y; w[4 * j + 2] = q4.z; w[4 * j + 3] = q4.w;
        }
        const float4 tq = *(const float4*)(&ftbuf[cur][cc * TX + xg * 4]);
        const float tqa[4] = {tq.x, tq.y, tq.z, tq.w};
        #pragma unroll
        for (int dx = 0; dx < 13; ++dx)
          #pragma unroll
          for (int kk = 0; kk < 4; ++kk)
            acc[dx][kk] = fmaf(w[dx + kk], tqa[kk], acc[dx][kk]);
      }
    }
    // R9-proven single-barrier double-buffer schedule.
    if (k < NCHUNK - 1) stage_write(cur ^ 1);
    __syncthreads();
  }

  // --- cross-cg reduction (staging buffers dead now) ---
  if (comp && cg == 1) {
    float* rb = smem + tl * 52;
    #pragma unroll
    for (int dx = 0; dx < 13; ++dx)
      *(float4*)(rb + dx * 4) = make_float4(acc[dx][0], acc[dx][1], acc[dx][2], acc[dx][3]);
  }
  __syncthreads();
  if (comp && cg == 0) {
    const float* rb = smem + tl * 52;
    #pragma unroll
    for (int dx = 0; dx < 13; ++dx) {
      const float4 r = *(const float4*)(rb + dx * 4);
      acc[dx][0] += r.x; acc[dx][1] += r.y; acc[dx][2] += r.z; acc[dx][3] += r.w;
    }
  }
  __syncthreads();
  if (comp && cg == 0) {
    #pragma unroll
    for (int dx = 0; dx < 13; ++dx)
      #pragma unroll
      for (int kk = 0; kk < 4; ++kk)
        smem[(xg * 4 + kk) * NWIN + dy * 13 + dx] = acc[dx][kk];
  }
  __syncthreads();
  {
    float* gb = vol + ((size_t)(b * HW + y * W + x0) * 2 + ii) * NWIN;
    for (int u = 0; u < 22; ++u) {
      const int e = t + u * 256;
      if (e < TILE) {
        const int xl2 = e / NWIN;
        const int mm  = e - xl2 * NWIN;
        gb[(size_t)xl2 * (2 * NWIN) + mm] = smem[e];
      }
    }
  }
}

// ================= Kernel B: wave-per-pixel post-processing =================
__global__ __launch_bounds__(256) void post_kernel(
    const float* __restrict__ vol,  // [pix][2][169]
    const int*  __restrict__ lab,   // [4][64][64]
    float* __restrict__ out) {      // [2][32][64][64]
  const int blk  = blockIdx.x;
  const int t    = threadIdx.x;
  const int w    = t >> 6;
  const int lane = t & 63;
  const int pix  = blk * 4 + w;
  const int b = pix >> 12;
  const int y = (pix >> 6) & 63;
  const int x = pix & 63;

  __shared__ float accS[4][NCLS];
  accS[w][lane & 31] = 0.f;

  float vv[6];
  float lmax = -INFINITY;
  const float* vp = vol + (size_t)pix * NTOT;
  #pragma unroll
  for (int k = 0; k < 6; ++k) {
    const int e = lane + 64 * k;
    vv[k] = (e < NTOT) ? vp[e] : -INFINITY;
    lmax = fmaxf(lmax, vv[k]);
  }
  #pragma unroll
  for (int off = 32; off > 0; off >>= 1)
    lmax = fmaxf(lmax, __shfl_xor(lmax, off));

  float p[6];
  float lsum = 0.f;
  #pragma unroll
  for (int k = 0; k < 6; ++k) {
    const int e = lane + 64 * k;
    p[k] = (e < NTOT) ? __expf(vv[k] - lmax) : 0.f;
    lsum += p[k];
  }
  #pragma unroll
  for (int off = 32; off > 0; off >>= 1)
    lsum += __shfl_xor(lsum, off);
  const float rinv = 1.f / lsum;
  #pragma unroll
  for (int k = 0; k < 6; ++k) p[k] *= rinv;

  float a1_0 = -1.f, a2_0 = -1.f, a1_1 = -1.f, a2_1 = -1.f;
  int   j1_0 = 1 << 20, j2_0 = 1 << 20, j1_1 = 1 << 20, j2_1 = 1 << 20;
  #pragma unroll
  for (int k = 0; k < 6; ++k) {
    const int e = lane + 64 * k;
    if (e < NTOT) {
      const int r = (e >= NWIN) ? 1 : 0;
      const int m = e - r * NWIN;
      const float pv = p[k];
      if (r == 0) {
        if (better(pv, m, a1_0, j1_0)) { a2_0 = a1_0; j2_0 = j1_0; a1_0 = pv; j1_0 = m; }
        else if (better(pv, m, a2_0, j2_0)) { a2_0 = pv; j2_0 = m; }
      } else {
        if (better(pv, m, a1_1, j1_1)) { a2_1 = a1_1; j2_1 = j1_1; a1_1 = pv; j1_1 = m; }
        else if (better(pv, m, a2_1, j2_1)) { a2_1 = pv; j2_1 = m; }
      }
    }
  }
  #pragma unroll
  for (int off = 32; off > 0; off >>= 1) {
    {
      const float u1 = __shfl_xor(a1_0, off); const int q1 = __shfl_xor(j1_0, off);
      const float u2 = __shfl_xor(a2_0, off); const int q2 = __shfl_xor(j2_0, off);
      if (better(u1, q1, a1_0, j1_0)) {
        float nv2; int ni2;
        if (better(a1_0, j1_0, u2, q2)) { nv2 = a1_0; ni2 = j1_0; }
        else                            { nv2 = u2;   ni2 = q2; }
        a1_0 = u1; j1_0 = q1; a2_0 = nv2; j2_0 = ni2;
      } else if (better(u1, q1, a2_0, j2_0)) { a2_0 = u1; j2_0 = q1; }
    }
    {
      const float u1 = __shfl_xor(a1_1, off); const int q1 = __shfl_xor(j1_1, off);
      const float u2 = __shfl_xor(a2_1, off); const int q2 = __shfl_xor(j2_1, off);
      if (better(u1, q1, a1_1, j1_1)) {
        float nv2; int ni2;
        if (better(a1_1, j1_1, u2, q2)) { nv2 = a1_1; ni2 = j1_1; }
        else                            { nv2 = u2;   ni2 = q2; }
        a1_1 = u1; j1_1 = q1; a2_1 = nv2; j2_1 = ni2;
      } else if (better(u1, q1, a2_1, j2_1)) { a2_1 = u1; j2_1 = q1; }
    }
  }

  const float e10 = __expf(a1_0), e20 = __expf(a2_0);
  const float rs0 = 1.f / (e10 + e20);
  const float w00 = e10 * rs0, w10 = e20 * rs0;
  const bool  fl0 = (a1_0 > 0.1f);
  const float xs00 = (float)(j1_0 % P), ys00 = (float)(j1_0 / P);
  const float xs10 = (float)(j2_0 % P), ys10 = (float)(j2_0 / P);

  const float e11 = __expf(a1_1), e21 = __expf(a2_1);
  const float rs1 = 1.f / (e11 + e21);
  const float w01 = e11 * rs1, w11 = e21 * rs1;
  const bool  fl1 = (a1_1 > 0.1f);
  const float xs01 = (float)(j1_1 % P), ys01 = (float)(j1_1 / P);
  const float xs11 = (float)(j2_1 % P), ys11 = (float)(j2_1 / P);

  #pragma unroll
  for (int k = 0; k < 6; ++k) {
    const int e = lane + 64 * k;
    if (e < NTOT) {
      const int r  = (e >= NWIN) ? 1 : 0;
      const int m  = e - r * NWIN;
      const int dy = m / P;
      const int dx = m - dy * P;
      const bool  fl = r ? fl1 : fl0;
      float val;
      if (fl) {
        const float wA = r ? w01 : w00, wB = r ? w11 : w10;
        const float xA = r ? xs01 : xs00, yA = r ? ys01 : ys00;
        const float xB = r ? xs11 : xs10, yB = r ? ys11 : ys10;
        const float fdx0 = (float)dx - xA, fdy0 = (float)dy - yA;
        const float fdx1 = (float)dx - xB, fdy1 = (float)dy - yB;
        val = wA * __expf(-FOUR_LN2 * (fdx0 * fdx0 + fdy0 * fdy0))
            + wB * __expf(-FOUR_LN2 * (fdx1 * fdx1 + fdy1 * fdy1));
      } else {
        val = p[k];
      }
      const int yy = y + dy - RAD;
      const int xx = x + dx - RAD;
      if ((unsigned)yy < 64u && (unsigned)xx < 64u) {
        const int cls = lab[(size_t)(r * 2 + b) * 4096 + yy * W + xx];
        atomicAdd(&accS[w][cls], val);
      }
    }
  }
  __syncthreads();

  if (t < 4 * NCLS) {
    const int cls = t >> 2;
    const int j   = t & 3;
    const int x0  = (blk * 4) & 63;
    const float sc = (cls == 0) ? 1.0f : 1.15f;
    out[(size_t)(b * NCLS + cls) * HW + y * W + x0 + j] = accS[j][cls] * sc;
  }
}

}  // namespace

extern "C" void kernel_launch(void* const* d_in, const int* in_sizes, int n_in,
                              void* d_out, int out_size, void* d_ws, size_t ws_size,
                              hipStream_t stream) {
  const float* fr = (const float*)d_in[0];   // feats_r
  const float* ft = (const float*)d_in[1];   // feats_t
  const int*   q  = (const int*)d_in[2];     // quantized_r
  float* out = (float*)d_out;
  float* vol = (float*)d_ws;                                   // 11,075,584 B
  int*   lab = (int*)((char*)d_ws + VOLF * sizeof(float));     // +64 KB

  corr_kernel<<<dim3(2 * 2 * 64 * 2), dim3(256), 0, stream>>>(fr, ft, vol, q, lab);
  post_kernel<<<dim3(2 * HW / 4), dim3(256), 0, stream>>>(vol, lab, out);
}